// Round 14
// baseline (497.180 us; speedup 1.0000x reference)
//
#include <hip/hip_runtime.h>
#include <stdint.h>

#define D 64          // embedding dim
#define SH_I 8        // item rows per bucket = 256
#define SH_U 9        // user rows per bucket = 512
#define EPT 8         // edges per thread in passA
#define TILE 4096     // 512 threads * EPT
#define PAD 8         // staging segment alignment (records) = 64B sector
#define SRT_CAP 18944 // LDS sorted-CSR buffer (4B recs) = 74KB

typedef unsigned long long u64;
typedef unsigned int u32;

#define DUMMY64 0xFFFFFFFF00000000ull

// ---------------- bf16 helpers ----------------

__device__ __forceinline__ u32 bf16_rne(float f) {
    u32 x = __float_as_uint(f);
    return (x + 0x7fffu + ((x >> 16) & 1u)) >> 16;
}
__device__ __forceinline__ u32 pack2_bf16(float a, float b) {
    return bf16_rne(a) | (bf16_rne(b) << 16);
}

// f32 -> packed bf16 in two planes of 16 u32 (64B) per row:
// plane (c>>4) holds u32 cols (c&15); planes separated by N*16 u32.
__global__ __launch_bounds__(256)
void cvt_bf16_kernel(const float2* __restrict__ src, u32* __restrict__ dst, int N) {
    long n = (long)N * 32;
    long i = (long)blockIdx.x * blockDim.x + threadIdx.x;
    long stride = (long)gridDim.x * blockDim.x;
    for (; i < n; i += stride) {
        float2 f = src[i];
        long row = i >> 5;
        int c = (int)(i & 31);
        dst[(size_t)(c >> 4) * N * 16 + row * 16 + (c & 15)] = pack2_bf16(f.x, f.y);
    }
}

// ---------------- scan helpers ----------------

__device__ __forceinline__ int excl_scan_512t(int v, int* wsum) {
    int tid = threadIdx.x, lane = tid & 63, wid = tid >> 6;
    int x = v;
    #pragma unroll
    for (int d = 1; d < 64; d <<= 1) { int t = __shfl_up(x, d, 64); if (lane >= d) x += t; }
    if (lane == 63) wsum[wid] = x;
    __syncthreads();
    if (tid < 8) {
        int y = wsum[tid];
        #pragma unroll
        for (int d = 1; d < 8; d <<= 1) { int t = __shfl_up(y, d, 8); if (tid >= d) y += t; }
        wsum[tid] = y;
    }
    __syncthreads();
    return ((wid > 0) ? wsum[wid - 1] : 0) + x - v;
}

__device__ __forceinline__ int excl_scan_1024t(int v, int* wsum16) {
    int tid = threadIdx.x, lane = tid & 63, wid = tid >> 6;
    int x = v;
    #pragma unroll
    for (int d = 1; d < 64; d <<= 1) { int t = __shfl_up(x, d, 64); if (lane >= d) x += t; }
    if (lane == 63) wsum16[wid] = x;
    __syncthreads();
    if (tid < 16) {
        int y = wsum16[tid];
        #pragma unroll
        for (int d = 1; d < 16; d <<= 1) { int t = __shfl_up(y, d, 16); if (tid >= d) y += t; }
        wsum16[tid] = y;
    }
    __syncthreads();
    return ((wid > 0) ? wsum16[wid - 1] : 0) + x - v;
}

// ---------------- CSR build ----------------
// Edge record (4B): [val_bf16_sans_sign:15 | src:17]   (val > 0 always)
// Staging record (8B): [dst_in_bucket:32][rec:32]; dummy has dst = 0xFFFFFFFF

__global__ __launch_bounds__(512)
void init_cursors_kernel(int* cur_i, int* rc_i, int nb_i, int cap_i,
                         int* cur_u, int* rc_u, int nb_u, int cap_u) {
    int t = threadIdx.x;
    if (t < nb_i) { cur_i[t] = t * cap_i; rc_i[t] = 0; }
    if (t < nb_u) { cur_u[t] = t * cap_u; rc_u[t] = 0; }
}

// LDS-sorted binning: histogram -> LDS scan -> LDS scatter -> per-bucket
// burst copy to 64B-aligned global segments (full-sector writes, amp ~1).
// Burst copy: 4 buckets per wave x 16 lanes each (cp ~16-24 -> high lane use).
__global__ __launch_bounds__(512)
void passA_kernel(const int* __restrict__ eu, const int* __restrict__ ei,
                  const float* __restrict__ ev, int E,
                  int* __restrict__ cur_i, int* __restrict__ rc_i,
                  int* __restrict__ cur_u, int* __restrict__ rc_u,
                  u64* __restrict__ stg_i, u64* __restrict__ stg_u) {
    __shared__ u64 stage[TILE];            // 32KB sorted staging
    __shared__ int cnt[256], loffs[256], gbase[256];
    __shared__ int wsum[8];
    int tid = threadIdx.x;
    long tile0 = (long)blockIdx.x * TILE;
    int uu[EPT], ii[EPT], lo[EPT];
    u32 vv[EPT];
    #pragma unroll
    for (int j = 0; j < EPT; ++j) {
        long e = tile0 + tid + j * 512;
        if (e < E) {
            uu[j] = eu[e]; ii[j] = ei[e];
            vv[j] = bf16_rne(ev[e]) & 0x7fffu;
        } else {
            uu[j] = -1;
        }
    }

    // ---------- direction: dst = item (bucket = ii>>SH_I, src = uu) ----------
    if (tid < 256) cnt[tid] = 0;
    __syncthreads();
    #pragma unroll
    for (int j = 0; j < EPT; ++j)
        if (uu[j] >= 0) lo[j] = atomicAdd(&cnt[ii[j] >> SH_I], 1);
    __syncthreads();
    {
        int c = (tid < 256) ? cnt[tid] : 0;
        int excl = excl_scan_512t(c, wsum);
        if (tid < 256) {
            loffs[tid] = excl;
            if (c) {
                int cp = (c + PAD - 1) & ~(PAD - 1);
                gbase[tid] = atomicAdd(&cur_i[tid], cp);
                atomicAdd(&rc_i[tid], c);
            }
        }
    }
    __syncthreads();
    #pragma unroll
    for (int j = 0; j < EPT; ++j) {
        if (uu[j] >= 0) {
            int b = ii[j] >> SH_I;
            u32 rec = (vv[j] << 17) | (u32)uu[j];
            stage[loffs[b] + lo[j]] =
                ((u64)(u32)(ii[j] & ((1 << SH_I) - 1)) << 32) | rec;
        }
    }
    __syncthreads();
    {
        int w = tid >> 6, lane = tid & 63;
        int sub = lane >> 4, l16 = lane & 15;
        for (int b = w * 4 + sub; b < 256; b += 32) {
            int c = cnt[b];
            if (!c) continue;
            int cp = (c + PAD - 1) & ~(PAD - 1);
            int lb = loffs[b];
            long gb = gbase[b];
            for (int r = l16; r < cp; r += 16)
                stg_i[gb + r] = (r < c) ? stage[lb + r] : DUMMY64;
        }
    }
    __syncthreads();

    // ---------- direction: dst = user (bucket = uu>>SH_U, src = ii) ----------
    if (tid < 256) cnt[tid] = 0;
    __syncthreads();
    #pragma unroll
    for (int j = 0; j < EPT; ++j)
        if (uu[j] >= 0) lo[j] = atomicAdd(&cnt[uu[j] >> SH_U], 1);
    __syncthreads();
    {
        int c = (tid < 256) ? cnt[tid] : 0;
        int excl = excl_scan_512t(c, wsum);
        if (tid < 256) {
            loffs[tid] = excl;
            if (c) {
                int cp = (c + PAD - 1) & ~(PAD - 1);
                gbase[tid] = atomicAdd(&cur_u[tid], cp);
                atomicAdd(&rc_u[tid], c);
            }
        }
    }
    __syncthreads();
    #pragma unroll
    for (int j = 0; j < EPT; ++j) {
        if (uu[j] >= 0) {
            int b = uu[j] >> SH_U;
            u32 rec = (vv[j] << 17) | (u32)ii[j];
            stage[loffs[b] + lo[j]] =
                ((u64)(u32)(uu[j] & ((1 << SH_U) - 1)) << 32) | rec;
        }
    }
    __syncthreads();
    {
        int w = tid >> 6, lane = tid & 63;
        int sub = lane >> 4, l16 = lane & 15;
        for (int b = w * 4 + sub; b < 256; b += 32) {
            int c = cnt[b];
            if (!c) continue;
            int cp = (c + PAD - 1) & ~(PAD - 1);
            int lb = loffs[b];
            long gb = gbase[b];
            for (int r = l16; r < cp; r += 16)
                stg_u[gb + r] = (r < c) ? stage[lb + r] : DUMMY64;
        }
    }
}

// exclusive scan of per-bucket REAL counts -> CSR bucket bases; write sentinel
__global__ __launch_bounds__(512)
void bucket_scan_kernel(const int* __restrict__ rc, int nb, int E,
                        int* __restrict__ bbase, int* __restrict__ rowp_sentinel) {
    __shared__ int wsum[8];
    int tid = threadIdx.x;
    int v = (tid < nb) ? rc[tid] : 0;
    int excl = excl_scan_512t(v, wsum);
    if (tid < nb) bbase[tid] = excl;
    if (tid == 0) *rowp_sentinel = E;
}

// Per bucket: histogram -> scan -> rowptr; scatter records into LDS sorted by
// row; burst-copy the sorted run to CSR (coalesced, write amp ~1).
__global__ __launch_bounds__(1024)
void passB_kernel(int nb_i, int cap_i, int N_i,
                  int nb_u, int cap_u, int N_u,
                  const int* __restrict__ cur_i, const int* __restrict__ cur_u,
                  const int* __restrict__ rc_i, const int* __restrict__ rc_u,
                  const int* __restrict__ bb_i, const int* __restrict__ bb_u,
                  const u64* __restrict__ stg_i, const u64* __restrict__ stg_u,
                  int* __restrict__ rowp_i, int* __restrict__ rowp_u,
                  u32* __restrict__ csr_i, u32* __restrict__ csr_u) {
    __shared__ u32 srt[SRT_CAP];
    __shared__ int lcnt[512];
    __shared__ int wsum[16];
    int b = blockIdx.x;
    int dir_item = (b < nb_i);
    int bb = dir_item ? b : b - nb_i;
    int SH = dir_item ? SH_I : SH_U;
    int cap = dir_item ? cap_i : cap_u;
    int N = dir_item ? N_i : N_u;
    const u64* stg = dir_item ? stg_i : stg_u;
    int ebase = dir_item ? bb_i[bb] : bb_u[bb];
    int scount = (dir_item ? cur_i[bb] : cur_u[bb]) - bb * cap;   // incl. dummies
    int realcnt = dir_item ? rc_i[bb] : rc_u[bb];
    int* rowp = dir_item ? rowp_i : rowp_u;
    u32* csr = dir_item ? csr_i : csr_u;

    int rows0 = bb << SH;
    int nrows = min(1 << SH, N - rows0);
    int tid = threadIdx.x;
    const uint4* stg4 = (const uint4*)(stg + (size_t)bb * cap);
    int npair = scount >> 1;                 // scount is a multiple of PAD=8

    if (tid < 512) lcnt[tid] = 0;
    __syncthreads();
    for (int k = tid; k < npair; k += 1024) {
        uint4 w = stg4[k];
        if ((int)w.y >= 0) atomicAdd(&lcnt[(int)w.y], 1);
        if ((int)w.w >= 0) atomicAdd(&lcnt[(int)w.w], 1);
    }
    __syncthreads();
    int v = (tid < 512) ? lcnt[tid] : 0;
    int excl = excl_scan_1024t(v, wsum);
    if (tid < 512) lcnt[tid] = excl;         // becomes bucket-local running cursor
    if (tid < nrows) rowp[rows0 + tid] = ebase + excl;
    __syncthreads();
    // scatter into LDS sorted by row (guard vs statistically-impossible overflow)
    for (int k = tid; k < npair; k += 1024) {
        uint4 w = stg4[k];
        if ((int)w.y >= 0) {
            int p = atomicAdd(&lcnt[(int)w.y], 1);
            if (p < SRT_CAP) srt[p] = w.x;
        }
        if ((int)w.w >= 0) {
            int p = atomicAdd(&lcnt[(int)w.w], 1);
            if (p < SRT_CAP) srt[p] = w.z;
        }
    }
    __syncthreads();
    // coalesced burst copy to global CSR
    int n = min(realcnt, SRT_CAP);
    for (int k = tid; k < n; k += 1024)
        csr[ebase + k] = srt[k];
}

// ---------------- propagation ----------------

// Half-D (plane) wave-per-row SpMM: lane = (g:3 | el:3). 8 edge-subgroups,
// unroll 2 -> 16 edges in flight. Gathers 64B plane rows (srcp = plane base,
// row stride 16 u32 = 8 u64). NT loads on the CSR stream keep the plane hot.
__global__ __launch_bounds__(256)
void spmm_half_kernel(const int* __restrict__ rowptr, const u32* __restrict__ csr,
                      const u32* __restrict__ srcp, u32* __restrict__ dstp,
                      int nrows) {
    int row = blockIdx.x * 4 + (threadIdx.x >> 6);
    if (row >= nrows) return;
    int lane = threadIdx.x & 63;
    int g = lane >> 3;
    int el = lane & 7;
    int beg = rowptr[row], end = rowptr[row + 1];
    const uint2* SB = (const uint2*)srcp + el;   // row stride = 8 uint2 (64B)
    float4 A0 = {0,0,0,0}, A1 = {0,0,0,0};
    for (int k = beg + g; k < end; k += 16) {
        u32 r0 = __builtin_nontemporal_load(csr + k);
        u32 r1 = __builtin_nontemporal_load(csr + k + 8);
        bool m1 = (k + 8) < end;
        int s0 = (int)(r0 & 0x1ffffu);
        int s1 = m1 ? (int)(r1 & 0x1ffffu) : 0;
        float v0 = __uint_as_float((r0 & 0xfffe0000u) >> 1);
        float v1 = m1 ? __uint_as_float((r1 & 0xfffe0000u) >> 1) : 0.f;
        uint2 w0 = SB[(size_t)s0 * 8];
        uint2 w1 = SB[(size_t)s1 * 8];
        A0.x += v0 * __uint_as_float(w0.x << 16);
        A0.y += v0 * __uint_as_float(w0.x & 0xffff0000u);
        A0.z += v0 * __uint_as_float(w0.y << 16);
        A0.w += v0 * __uint_as_float(w0.y & 0xffff0000u);
        A1.x += v1 * __uint_as_float(w1.x << 16);
        A1.y += v1 * __uint_as_float(w1.x & 0xffff0000u);
        A1.z += v1 * __uint_as_float(w1.y << 16);
        A1.w += v1 * __uint_as_float(w1.y & 0xffff0000u);
    }
    float4 a;
    a.x = A0.x + A1.x; a.y = A0.y + A1.y; a.z = A0.z + A1.z; a.w = A0.w + A1.w;
    #pragma unroll
    for (int m = 8; m < 64; m <<= 1) {
        a.x += __shfl_xor(a.x, m, 64);
        a.y += __shfl_xor(a.y, m, 64);
        a.z += __shfl_xor(a.z, m, 64);
        a.w += __shfl_xor(a.w, m, 64);
    }
    if (g == 0) {
        u64 o = (u64)pack2_bf16(a.x, a.y) | ((u64)pack2_bf16(a.z, a.w) << 32);
        __builtin_nontemporal_store(o, (u64*)dstp + (size_t)row * 8 + el);
    }
}

// Sampled full-width SpMM (layer 3): row = idx[slot]; source is plane-split
// (splaneN = source table row count); output full-width by slot.
__global__ __launch_bounds__(256)
void spmm_sampled_kernel(const int* __restrict__ rowptr, const u32* __restrict__ csr,
                         const u32* __restrict__ src_base, int splaneN,
                         u32* __restrict__ dst16, const int* __restrict__ idx,
                         int nrows) {
    int slot = blockIdx.x * 4 + (threadIdx.x >> 6);
    if (slot >= nrows) return;
    int row = idx[slot];
    int lane = threadIdx.x & 63;
    int g = lane >> 4;
    int el = lane & 15;
    int beg = rowptr[row], end = rowptr[row + 1];
    const uint2* SB = (const uint2*)(src_base + (size_t)(el >> 3) * splaneN * 16)
                      + (el & 7);            // plane row stride = 8 uint2
    float4 A0 = {0,0,0,0}, A1 = {0,0,0,0}, A2 = {0,0,0,0}, A3 = {0,0,0,0};
    for (int k = beg + g; k < end; k += 16) {
        u32 r0 = csr[k];
        u32 r1 = csr[k + 4];
        u32 r2 = csr[k + 8];
        u32 r3 = csr[k + 12];
        bool m1 = (k + 4) < end, m2 = (k + 8) < end, m3 = (k + 12) < end;
        int s0 = (int)(r0 & 0x1ffffu);
        int s1 = m1 ? (int)(r1 & 0x1ffffu) : 0;
        int s2 = m2 ? (int)(r2 & 0x1ffffu) : 0;
        int s3 = m3 ? (int)(r3 & 0x1ffffu) : 0;
        float v0 = __uint_as_float((r0 & 0xfffe0000u) >> 1);
        float v1 = m1 ? __uint_as_float((r1 & 0xfffe0000u) >> 1) : 0.f;
        float v2 = m2 ? __uint_as_float((r2 & 0xfffe0000u) >> 1) : 0.f;
        float v3 = m3 ? __uint_as_float((r3 & 0xfffe0000u) >> 1) : 0.f;
        uint2 w0 = SB[(size_t)s0 * 8];
        uint2 w1 = SB[(size_t)s1 * 8];
        uint2 w2 = SB[(size_t)s2 * 8];
        uint2 w3 = SB[(size_t)s3 * 8];
        A0.x += v0 * __uint_as_float(w0.x << 16);
        A0.y += v0 * __uint_as_float(w0.x & 0xffff0000u);
        A0.z += v0 * __uint_as_float(w0.y << 16);
        A0.w += v0 * __uint_as_float(w0.y & 0xffff0000u);
        A1.x += v1 * __uint_as_float(w1.x << 16);
        A1.y += v1 * __uint_as_float(w1.x & 0xffff0000u);
        A1.z += v1 * __uint_as_float(w1.y << 16);
        A1.w += v1 * __uint_as_float(w1.y & 0xffff0000u);
        A2.x += v2 * __uint_as_float(w2.x << 16);
        A2.y += v2 * __uint_as_float(w2.x & 0xffff0000u);
        A2.z += v2 * __uint_as_float(w2.y << 16);
        A2.w += v2 * __uint_as_float(w2.y & 0xffff0000u);
        A3.x += v3 * __uint_as_float(w3.x << 16);
        A3.y += v3 * __uint_as_float(w3.x & 0xffff0000u);
        A3.z += v3 * __uint_as_float(w3.y << 16);
        A3.w += v3 * __uint_as_float(w3.y & 0xffff0000u);
    }
    float4 a;
    a.x = (A0.x + A1.x) + (A2.x + A3.x);
    a.y = (A0.y + A1.y) + (A2.y + A3.y);
    a.z = (A0.z + A1.z) + (A2.z + A3.z);
    a.w = (A0.w + A1.w) + (A2.w + A3.w);
    a.x += __shfl_xor(a.x, 16, 64); a.x += __shfl_xor(a.x, 32, 64);
    a.y += __shfl_xor(a.y, 16, 64); a.y += __shfl_xor(a.y, 32, 64);
    a.z += __shfl_xor(a.z, 16, 64); a.z += __shfl_xor(a.z, 32, 64);
    a.w += __shfl_xor(a.w, 16, 64); a.w += __shfl_xor(a.w, 32, 64);
    if (g == 0) {
        ((uint2*)dst16)[(size_t)slot * 16 + el] =
            make_uint2(pack2_bf16(a.x, a.y), pack2_bf16(a.z, a.w));
    }
}

// Final score: per sampled pair, sum orig f32 + e1,e2 (plane-split, by id)
// + e3 (full-width, by slot), dot, scale. 16 lanes per pair.
__global__ __launch_bounds__(256)
void score_kernel(const float* __restrict__ user_emb, const float* __restrict__ item_emb,
                  const u32* __restrict__ eu1, const u32* __restrict__ eu2,
                  const u32* __restrict__ eu3s,
                  const u32* __restrict__ ei1, const u32* __restrict__ ei2,
                  const u32* __restrict__ ei3s,
                  const int* __restrict__ users, const int* __restrict__ items,
                  float* __restrict__ out, int B, int U, int I, float inv2) {
    int gid = blockIdx.x * blockDim.x + threadIdx.x;
    int b = gid >> 4;
    int lane = gid & 15;
    if (b >= B) return;
    int u = users[b], it = items[b];
    size_t upoff = (size_t)(lane >> 3) * U * 16;   // plane offset (u32 units)
    size_t ipoff = (size_t)(lane >> 3) * I * 16;
    int col = lane & 7;

    float4 su = ((const float4*)(user_emb + (size_t)u * D))[lane];
    uint2 p1 = ((const uint2*)(eu1 + upoff))[(size_t)u * 8 + col];
    uint2 p2 = ((const uint2*)(eu2 + upoff))[(size_t)u * 8 + col];
    uint2 p3 = ((const uint2*)eu3s)[(size_t)b * 16 + lane];
    su.x += __uint_as_float(p1.x << 16) + __uint_as_float(p2.x << 16) + __uint_as_float(p3.x << 16);
    su.y += __uint_as_float(p1.x & 0xffff0000u) + __uint_as_float(p2.x & 0xffff0000u) + __uint_as_float(p3.x & 0xffff0000u);
    su.z += __uint_as_float(p1.y << 16) + __uint_as_float(p2.y << 16) + __uint_as_float(p3.y << 16);
    su.w += __uint_as_float(p1.y & 0xffff0000u) + __uint_as_float(p2.y & 0xffff0000u) + __uint_as_float(p3.y & 0xffff0000u);

    float4 si = ((const float4*)(item_emb + (size_t)it * D))[lane];
    uint2 q1 = ((const uint2*)(ei1 + ipoff))[(size_t)it * 8 + col];
    uint2 q2 = ((const uint2*)(ei2 + ipoff))[(size_t)it * 8 + col];
    uint2 q3 = ((const uint2*)ei3s)[(size_t)b * 16 + lane];
    si.x += __uint_as_float(q1.x << 16) + __uint_as_float(q2.x << 16) + __uint_as_float(q3.x << 16);
    si.y += __uint_as_float(q1.x & 0xffff0000u) + __uint_as_float(q2.x & 0xffff0000u) + __uint_as_float(q3.x & 0xffff0000u);
    si.z += __uint_as_float(q1.y << 16) + __uint_as_float(q2.y << 16) + __uint_as_float(q3.y << 16);
    si.w += __uint_as_float(q1.y & 0xffff0000u) + __uint_as_float(q2.y & 0xffff0000u) + __uint_as_float(q3.y & 0xffff0000u);

    float d = su.x * si.x + su.y * si.y + su.z * si.z + su.w * si.w;
    #pragma unroll
    for (int m = 1; m < 16; m <<= 1) d += __shfl_xor(d, m, 64);
    if (lane == 0) out[b] = d * inv2;
}

// ---------------- launch ----------------

extern "C" void kernel_launch(void* const* d_in, const int* in_sizes, int n_in,
                              void* d_out, int out_size, void* d_ws, size_t ws_size,
                              hipStream_t stream) {
    const float* user_emb = (const float*)d_in[0];
    const float* item_emb = (const float*)d_in[1];
    const float* edge_vals = (const float*)d_in[2];
    const int* edge_u = (const int*)d_in[3];
    const int* edge_i = (const int*)d_in[4];
    const int* users = (const int*)d_in[5];
    const int* items = (const int*)d_in[6];
    float* out = (float*)d_out;

    const int U = in_sizes[0] / D;
    const int I = in_sizes[1] / D;
    const int E = in_sizes[2];
    const int B = in_sizes[5];

    const int nb_i = (I + (1 << SH_I) - 1) >> SH_I;
    const int nb_u = (U + (1 << SH_U) - 1) >> SH_U;
    const int tiles = (E + TILE - 1) / TILE;
    // cap: mean real + worst-case pad (PAD-1 per block) + variance slack
    const int cap_i = ((E / nb_i + tiles * (PAD - 1) + 1024 + 63) / 64) * 64;
    const int cap_u = ((E / nb_u + tiles * (PAD - 1) + 1024 + 63) / 64) * 64;

    // carve workspace (256B aligned)
    char* p = (char*)d_ws;
    size_t off = 0;
    auto alloc = [&](size_t bytes) -> char* {
        char* r = p + off;
        off = (off + bytes + 255) & ~(size_t)255;
        return r;
    };
    u32* ub16  = (u32*)alloc((size_t)U * (D / 2) * 4);  // bf16, 2 planes of 64B rows
    u32* ib16  = (u32*)alloc((size_t)I * (D / 2) * 4);
    u32* eu1   = (u32*)alloc((size_t)U * (D / 2) * 4);  // dense layer tables (planes)
    u32* eu2   = (u32*)alloc((size_t)U * (D / 2) * 4);
    u32* ei1   = (u32*)alloc((size_t)I * (D / 2) * 4);
    u32* ei2   = (u32*)alloc((size_t)I * (D / 2) * 4);
    u32* eu3s  = (u32*)alloc((size_t)B * (D / 2) * 4);  // sampled layer-3, full-width
    u32* ei3s  = (u32*)alloc((size_t)B * (D / 2) * 4);
    u32* csr_u = (u32*)alloc((size_t)(E + 16) * 4);
    u32* csr_i = (u32*)alloc((size_t)(E + 16) * 4);
    int* rowp_u = (int*)alloc((size_t)(U + 1) * 4);
    int* rowp_i = (int*)alloc((size_t)(I + 1) * 4);
    int* cur_i  = (int*)alloc((size_t)nb_i * 4);
    int* cur_u  = (int*)alloc((size_t)nb_u * 4);
    int* rc_i   = (int*)alloc((size_t)nb_i * 4);
    int* rc_u   = (int*)alloc((size_t)nb_u * 4);
    int* bb_i   = (int*)alloc((size_t)nb_i * 4);
    int* bb_u   = (int*)alloc((size_t)nb_u * 4);
    u64* stg_i  = (u64*)alloc((size_t)nb_i * cap_i * 8);
    u64* stg_u  = (u64*)alloc((size_t)nb_u * cap_u * 8);
    if (off > ws_size) return;    // workspace too small -> fail loudly

    // 0. convert original embeddings to plane-split bf16 tables
    cvt_bf16_kernel<<<1024, 256, 0, stream>>>((const float2*)user_emb, ub16, U);
    cvt_bf16_kernel<<<1024, 256, 0, stream>>>((const float2*)item_emb, ib16, I);

    // 1. CSR build (both directions)
    init_cursors_kernel<<<1, 512, 0, stream>>>(cur_i, rc_i, nb_i, cap_i,
                                               cur_u, rc_u, nb_u, cap_u);
    passA_kernel<<<tiles, 512, 0, stream>>>(edge_u, edge_i, edge_vals, E,
                                            cur_i, rc_i, cur_u, rc_u,
                                            stg_i, stg_u);
    bucket_scan_kernel<<<1, 512, 0, stream>>>(rc_i, nb_i, E, bb_i, rowp_i + I);
    bucket_scan_kernel<<<1, 512, 0, stream>>>(rc_u, nb_u, E, bb_u, rowp_u + U);
    passB_kernel<<<nb_i + nb_u, 1024, 0, stream>>>(nb_i, cap_i, I, nb_u, cap_u, U,
                                                   cur_i, cur_u, rc_i, rc_u,
                                                   bb_i, bb_u,
                                                   stg_i, stg_u, rowp_i, rowp_u,
                                                   csr_i, csr_u);

    // 2. propagation: layers 1-2 dense (plane-split passes), layer 3 sampled
    int blk_i = (I + 3) / 4;
    int blk_u = (U + 3) / 4;
    int blk_s = (B + 3) / 4;
    const size_t UP = (size_t)U * 16, IP = (size_t)I * 16;   // plane strides (u32)
    // layer 1
    spmm_half_kernel<<<blk_i, 256, 0, stream>>>(rowp_i, csr_i, ub16,      ei1,      I);
    spmm_half_kernel<<<blk_i, 256, 0, stream>>>(rowp_i, csr_i, ub16 + UP, ei1 + IP, I);
    spmm_half_kernel<<<blk_u, 256, 0, stream>>>(rowp_u, csr_u, ib16,      eu1,      U);
    spmm_half_kernel<<<blk_u, 256, 0, stream>>>(rowp_u, csr_u, ib16 + IP, eu1 + UP, U);
    // layer 2
    spmm_half_kernel<<<blk_i, 256, 0, stream>>>(rowp_i, csr_i, eu1,      ei2,      I);
    spmm_half_kernel<<<blk_i, 256, 0, stream>>>(rowp_i, csr_i, eu1 + UP, ei2 + IP, I);
    spmm_half_kernel<<<blk_u, 256, 0, stream>>>(rowp_u, csr_u, ei1,      eu2,      U);
    spmm_half_kernel<<<blk_u, 256, 0, stream>>>(rowp_u, csr_u, ei1 + IP, eu2 + UP, U);
    // layer 3 (sampled rows only, full width)
    spmm_sampled_kernel<<<blk_s, 256, 0, stream>>>(rowp_i, csr_i, eu2, U, ei3s, items, B);
    spmm_sampled_kernel<<<blk_s, 256, 0, stream>>>(rowp_u, csr_u, ei2, I, eu3s, users, B);

    // 3. final scores for sampled pairs: sum four layers, dot, scale by 1/16
    int blk_sc = (B * 16 + 255) / 256;
    score_kernel<<<blk_sc, 256, 0, stream>>>(user_emb, item_emb,
                                             eu1, eu2, eu3s, ei1, ei2, ei3s,
                                             users, items, out, B, U, I, 0.0625f);
}

// Round 15
// 311.182 us; speedup vs baseline: 1.5977x; 1.5977x over previous
//
#include <hip/hip_runtime.h>
#include <stdint.h>

#define D 64          // embedding dim
#define SH_I 8        // item rows per bucket = 256
#define SH_U 9        // user rows per bucket = 512
#define EPT 8         // edges per thread in passA
#define TILE 4096     // 512 threads * EPT
#define PAD 8         // staging segment alignment (records) = 64B sector
#define SRT_CAP 18944 // LDS sorted-CSR buffer (4B recs) = 74KB

typedef unsigned long long u64;
typedef unsigned int u32;

#define DUMMY64 0xFFFFFFFF00000000ull

// ---------------- bf16 helpers ----------------

__device__ __forceinline__ u32 bf16_rne(float f) {
    u32 x = __float_as_uint(f);
    return (x + 0x7fffu + ((x >> 16) & 1u)) >> 16;
}
__device__ __forceinline__ u32 pack2_bf16(float a, float b) {
    return bf16_rne(a) | (bf16_rne(b) << 16);
}
__device__ __forceinline__ float blo(u32 w) { return __uint_as_float(w << 16); }
__device__ __forceinline__ float bhi(u32 w) { return __uint_as_float(w & 0xffff0000u); }

// f32 pairs -> packed bf16 (u32 holds 2 elems), row-major 128B rows
__global__ __launch_bounds__(256)
void cvt_bf16_kernel(const float2* __restrict__ src, u32* __restrict__ dst, long n2) {
    long i = (long)blockIdx.x * blockDim.x + threadIdx.x;
    long stride = (long)gridDim.x * blockDim.x;
    for (; i < n2; i += stride) {
        float2 f = src[i];
        dst[i] = pack2_bf16(f.x, f.y);
    }
}

// ---------------- scan helpers ----------------

__device__ __forceinline__ int excl_scan_512t(int v, int* wsum) {
    int tid = threadIdx.x, lane = tid & 63, wid = tid >> 6;
    int x = v;
    #pragma unroll
    for (int d = 1; d < 64; d <<= 1) { int t = __shfl_up(x, d, 64); if (lane >= d) x += t; }
    if (lane == 63) wsum[wid] = x;
    __syncthreads();
    if (tid < 8) {
        int y = wsum[tid];
        #pragma unroll
        for (int d = 1; d < 8; d <<= 1) { int t = __shfl_up(y, d, 8); if (tid >= d) y += t; }
        wsum[tid] = y;
    }
    __syncthreads();
    return ((wid > 0) ? wsum[wid - 1] : 0) + x - v;
}

__device__ __forceinline__ int excl_scan_1024t(int v, int* wsum16) {
    int tid = threadIdx.x, lane = tid & 63, wid = tid >> 6;
    int x = v;
    #pragma unroll
    for (int d = 1; d < 64; d <<= 1) { int t = __shfl_up(x, d, 64); if (lane >= d) x += t; }
    if (lane == 63) wsum16[wid] = x;
    __syncthreads();
    if (tid < 16) {
        int y = wsum16[tid];
        #pragma unroll
        for (int d = 1; d < 16; d <<= 1) { int t = __shfl_up(y, d, 16); if (tid >= d) y += t; }
        wsum16[tid] = y;
    }
    __syncthreads();
    return ((wid > 0) ? wsum16[wid - 1] : 0) + x - v;
}

// ---------------- CSR build ----------------
// Edge record (4B): [val_bf16_sans_sign:15 | src:17]   (val > 0 always)
// Staging record (8B): [dst_in_bucket:32][rec:32]; dummy has dst = 0xFFFFFFFF

__global__ __launch_bounds__(512)
void init_cursors_kernel(int* cur_i, int* rc_i, int nb_i, int cap_i,
                         int* cur_u, int* rc_u, int nb_u, int cap_u) {
    int t = threadIdx.x;
    if (t < nb_i) { cur_i[t] = t * cap_i; rc_i[t] = 0; }
    if (t < nb_u) { cur_u[t] = t * cap_u; rc_u[t] = 0; }
}

// LDS-sorted binning: histogram -> LDS scan -> LDS scatter -> per-bucket
// burst copy to 64B-aligned global segments (full-sector writes, amp ~1).
// Burst copy: 4 buckets per wave x 16 lanes each (cp ~16-24 -> high lane use).
__global__ __launch_bounds__(512)
void passA_kernel(const int* __restrict__ eu, const int* __restrict__ ei,
                  const float* __restrict__ ev, int E,
                  int* __restrict__ cur_i, int* __restrict__ rc_i,
                  int* __restrict__ cur_u, int* __restrict__ rc_u,
                  u64* __restrict__ stg_i, u64* __restrict__ stg_u) {
    __shared__ u64 stage[TILE];            // 32KB sorted staging
    __shared__ int cnt[256], loffs[256], gbase[256];
    __shared__ int wsum[8];
    int tid = threadIdx.x;
    long tile0 = (long)blockIdx.x * TILE;
    int uu[EPT], ii[EPT], lo[EPT];
    u32 vv[EPT];
    #pragma unroll
    for (int j = 0; j < EPT; ++j) {
        long e = tile0 + tid + j * 512;
        if (e < E) {
            uu[j] = eu[e]; ii[j] = ei[e];
            vv[j] = bf16_rne(ev[e]) & 0x7fffu;
        } else {
            uu[j] = -1;
        }
    }

    // ---------- direction: dst = item (bucket = ii>>SH_I, src = uu) ----------
    if (tid < 256) cnt[tid] = 0;
    __syncthreads();
    #pragma unroll
    for (int j = 0; j < EPT; ++j)
        if (uu[j] >= 0) lo[j] = atomicAdd(&cnt[ii[j] >> SH_I], 1);
    __syncthreads();
    {
        int c = (tid < 256) ? cnt[tid] : 0;
        int excl = excl_scan_512t(c, wsum);
        if (tid < 256) {
            loffs[tid] = excl;
            if (c) {
                int cp = (c + PAD - 1) & ~(PAD - 1);
                gbase[tid] = atomicAdd(&cur_i[tid], cp);
                atomicAdd(&rc_i[tid], c);
            }
        }
    }
    __syncthreads();
    #pragma unroll
    for (int j = 0; j < EPT; ++j) {
        if (uu[j] >= 0) {
            int b = ii[j] >> SH_I;
            u32 rec = (vv[j] << 17) | (u32)uu[j];
            stage[loffs[b] + lo[j]] =
                ((u64)(u32)(ii[j] & ((1 << SH_I) - 1)) << 32) | rec;
        }
    }
    __syncthreads();
    {
        int w = tid >> 6, lane = tid & 63;
        int sub = lane >> 4, l16 = lane & 15;
        for (int b = w * 4 + sub; b < 256; b += 32) {
            int c = cnt[b];
            if (!c) continue;
            int cp = (c + PAD - 1) & ~(PAD - 1);
            int lb = loffs[b];
            long gb = gbase[b];
            for (int r = l16; r < cp; r += 16)
                stg_i[gb + r] = (r < c) ? stage[lb + r] : DUMMY64;
        }
    }
    __syncthreads();

    // ---------- direction: dst = user (bucket = uu>>SH_U, src = ii) ----------
    if (tid < 256) cnt[tid] = 0;
    __syncthreads();
    #pragma unroll
    for (int j = 0; j < EPT; ++j)
        if (uu[j] >= 0) lo[j] = atomicAdd(&cnt[uu[j] >> SH_U], 1);
    __syncthreads();
    {
        int c = (tid < 256) ? cnt[tid] : 0;
        int excl = excl_scan_512t(c, wsum);
        if (tid < 256) {
            loffs[tid] = excl;
            if (c) {
                int cp = (c + PAD - 1) & ~(PAD - 1);
                gbase[tid] = atomicAdd(&cur_u[tid], cp);
                atomicAdd(&rc_u[tid], c);
            }
        }
    }
    __syncthreads();
    #pragma unroll
    for (int j = 0; j < EPT; ++j) {
        if (uu[j] >= 0) {
            int b = uu[j] >> SH_U;
            u32 rec = (vv[j] << 17) | (u32)ii[j];
            stage[loffs[b] + lo[j]] =
                ((u64)(u32)(uu[j] & ((1 << SH_U) - 1)) << 32) | rec;
        }
    }
    __syncthreads();
    {
        int w = tid >> 6, lane = tid & 63;
        int sub = lane >> 4, l16 = lane & 15;
        for (int b = w * 4 + sub; b < 256; b += 32) {
            int c = cnt[b];
            if (!c) continue;
            int cp = (c + PAD - 1) & ~(PAD - 1);
            int lb = loffs[b];
            long gb = gbase[b];
            for (int r = l16; r < cp; r += 16)
                stg_u[gb + r] = (r < c) ? stage[lb + r] : DUMMY64;
        }
    }
}

// exclusive scan of per-bucket REAL counts -> CSR bucket bases; write sentinel
__global__ __launch_bounds__(512)
void bucket_scan_kernel(const int* __restrict__ rc, int nb, int E,
                        int* __restrict__ bbase, int* __restrict__ rowp_sentinel) {
    __shared__ int wsum[8];
    int tid = threadIdx.x;
    int v = (tid < nb) ? rc[tid] : 0;
    int excl = excl_scan_512t(v, wsum);
    if (tid < nb) bbase[tid] = excl;
    if (tid == 0) *rowp_sentinel = E;
}

// Per bucket: histogram -> scan -> rowptr; scatter records into LDS sorted by
// row; burst-copy the sorted run to CSR (coalesced, write amp ~1).
__global__ __launch_bounds__(1024)
void passB_kernel(int nb_i, int cap_i, int N_i,
                  int nb_u, int cap_u, int N_u,
                  const int* __restrict__ cur_i, const int* __restrict__ cur_u,
                  const int* __restrict__ rc_i, const int* __restrict__ rc_u,
                  const int* __restrict__ bb_i, const int* __restrict__ bb_u,
                  const u64* __restrict__ stg_i, const u64* __restrict__ stg_u,
                  int* __restrict__ rowp_i, int* __restrict__ rowp_u,
                  u32* __restrict__ csr_i, u32* __restrict__ csr_u) {
    __shared__ u32 srt[SRT_CAP];
    __shared__ int lcnt[512];
    __shared__ int wsum[16];
    int b = blockIdx.x;
    int dir_item = (b < nb_i);
    int bb = dir_item ? b : b - nb_i;
    int SH = dir_item ? SH_I : SH_U;
    int cap = dir_item ? cap_i : cap_u;
    int N = dir_item ? N_i : N_u;
    const u64* stg = dir_item ? stg_i : stg_u;
    int ebase = dir_item ? bb_i[bb] : bb_u[bb];
    int scount = (dir_item ? cur_i[bb] : cur_u[bb]) - bb * cap;   // incl. dummies
    int realcnt = dir_item ? rc_i[bb] : rc_u[bb];
    int* rowp = dir_item ? rowp_i : rowp_u;
    u32* csr = dir_item ? csr_i : csr_u;

    int rows0 = bb << SH;
    int nrows = min(1 << SH, N - rows0);
    int tid = threadIdx.x;
    const uint4* stg4 = (const uint4*)(stg + (size_t)bb * cap);
    int npair = scount >> 1;                 // scount is a multiple of PAD=8

    if (tid < 512) lcnt[tid] = 0;
    __syncthreads();
    for (int k = tid; k < npair; k += 1024) {
        uint4 w = stg4[k];
        if ((int)w.y >= 0) atomicAdd(&lcnt[(int)w.y], 1);
        if ((int)w.w >= 0) atomicAdd(&lcnt[(int)w.w], 1);
    }
    __syncthreads();
    int v = (tid < 512) ? lcnt[tid] : 0;
    int excl = excl_scan_1024t(v, wsum);
    if (tid < 512) lcnt[tid] = excl;         // becomes bucket-local running cursor
    if (tid < nrows) rowp[rows0 + tid] = ebase + excl;
    __syncthreads();
    // scatter into LDS sorted by row (guard vs statistically-impossible overflow)
    for (int k = tid; k < npair; k += 1024) {
        uint4 w = stg4[k];
        if ((int)w.y >= 0) {
            int p = atomicAdd(&lcnt[(int)w.y], 1);
            if (p < SRT_CAP) srt[p] = w.x;
        }
        if ((int)w.w >= 0) {
            int p = atomicAdd(&lcnt[(int)w.w], 1);
            if (p < SRT_CAP) srt[p] = w.z;
        }
    }
    __syncthreads();
    // coalesced burst copy to global CSR
    int n = min(realcnt, SRT_CAP);
    for (int k = tid; k < n; k += 1024)
        csr[ebase + k] = srt[k];
}

// ---------------- propagation ----------------

// Wave-per-row SpMM over packed-bf16 128B rows, uint4 gathers.
// lane = (g:3 | el:3): 8 edge-subgroups x unroll 2 = 16 edges in flight;
// el indexes the row's uint4 (8 bf16 = dims el*8..el*8+7). 2 gather
// instructions per 16 edges (each 64 lanes x 16B = 8 full rows).
// 4B records: src = rec & 0x1ffff, val_f32_bits = (rec & 0xfffe0000) >> 1.
// SAMPLED: row = idx[slot], output keyed by slot (for last layer).
template<int SAMPLED>
__global__ __launch_bounds__(256)
void spmm_kernel(const int* __restrict__ rowptr, const u32* __restrict__ csr,
                 const u32* __restrict__ src16, u32* __restrict__ dst16,
                 const int* __restrict__ idx, int nrows) {
    int slot = blockIdx.x * 4 + (threadIdx.x >> 6);
    if (slot >= nrows) return;
    int row = SAMPLED ? idx[slot] : slot;
    int lane = threadIdx.x & 63;
    int g = lane >> 3;
    int el = lane & 7;
    int beg = rowptr[row], end = rowptr[row + 1];
    const uint4* SB = (const uint4*)src16 + el;   // row stride = 8 uint4 (128B)
    float A0[8] = {0,0,0,0,0,0,0,0}, A1[8] = {0,0,0,0,0,0,0,0};
    for (int k = beg + g; k < end; k += 16) {
        u32 r0 = csr[k];
        u32 r1 = csr[k + 8];
        bool m1 = (k + 8) < end;
        int s0 = (int)(r0 & 0x1ffffu);
        int s1 = m1 ? (int)(r1 & 0x1ffffu) : 0;
        float v0 = __uint_as_float((r0 & 0xfffe0000u) >> 1);
        float v1 = m1 ? __uint_as_float((r1 & 0xfffe0000u) >> 1) : 0.f;
        uint4 w0 = SB[(size_t)s0 * 8];
        uint4 w1 = SB[(size_t)s1 * 8];
        A0[0] += v0 * blo(w0.x); A0[1] += v0 * bhi(w0.x);
        A0[2] += v0 * blo(w0.y); A0[3] += v0 * bhi(w0.y);
        A0[4] += v0 * blo(w0.z); A0[5] += v0 * bhi(w0.z);
        A0[6] += v0 * blo(w0.w); A0[7] += v0 * bhi(w0.w);
        A1[0] += v1 * blo(w1.x); A1[1] += v1 * bhi(w1.x);
        A1[2] += v1 * blo(w1.y); A1[3] += v1 * bhi(w1.y);
        A1[4] += v1 * blo(w1.z); A1[5] += v1 * bhi(w1.z);
        A1[6] += v1 * blo(w1.w); A1[7] += v1 * bhi(w1.w);
    }
    float a[8];
    #pragma unroll
    for (int j = 0; j < 8; ++j) a[j] = A0[j] + A1[j];
    #pragma unroll
    for (int m = 8; m < 64; m <<= 1) {
        #pragma unroll
        for (int j = 0; j < 8; ++j) a[j] += __shfl_xor(a[j], m, 64);
    }
    if (g == 0) {
        uint4 o;
        o.x = pack2_bf16(a[0], a[1]);
        o.y = pack2_bf16(a[2], a[3]);
        o.z = pack2_bf16(a[4], a[5]);
        o.w = pack2_bf16(a[6], a[7]);
        ((uint4*)dst16)[(size_t)slot * 8 + el] = o;
    }
}

// Final score: per sampled pair, sum orig f32 + e1,e2 (by id) + e3 (by slot),
// dot, scale. 16 lanes per pair.
__global__ __launch_bounds__(256)
void score_kernel(const float* __restrict__ user_emb, const float* __restrict__ item_emb,
                  const u32* __restrict__ eu1, const u32* __restrict__ eu2,
                  const u32* __restrict__ eu3s,
                  const u32* __restrict__ ei1, const u32* __restrict__ ei2,
                  const u32* __restrict__ ei3s,
                  const int* __restrict__ users, const int* __restrict__ items,
                  float* __restrict__ out, int B, float inv2) {
    int gid = blockIdx.x * blockDim.x + threadIdx.x;
    int b = gid >> 4;
    int lane = gid & 15;
    if (b >= B) return;
    int u = users[b], it = items[b];

    float4 su = ((const float4*)(user_emb + (size_t)u * D))[lane];
    uint2 p1 = ((const uint2*)eu1)[(size_t)u * 16 + lane];
    uint2 p2 = ((const uint2*)eu2)[(size_t)u * 16 + lane];
    uint2 p3 = ((const uint2*)eu3s)[(size_t)b * 16 + lane];
    su.x += blo(p1.x) + blo(p2.x) + blo(p3.x);
    su.y += bhi(p1.x) + bhi(p2.x) + bhi(p3.x);
    su.z += blo(p1.y) + blo(p2.y) + blo(p3.y);
    su.w += bhi(p1.y) + bhi(p2.y) + bhi(p3.y);

    float4 si = ((const float4*)(item_emb + (size_t)it * D))[lane];
    uint2 q1 = ((const uint2*)ei1)[(size_t)it * 16 + lane];
    uint2 q2 = ((const uint2*)ei2)[(size_t)it * 16 + lane];
    uint2 q3 = ((const uint2*)ei3s)[(size_t)b * 16 + lane];
    si.x += blo(q1.x) + blo(q2.x) + blo(q3.x);
    si.y += bhi(q1.x) + bhi(q2.x) + bhi(q3.x);
    si.z += blo(q1.y) + blo(q2.y) + blo(q3.y);
    si.w += bhi(q1.y) + bhi(q2.y) + bhi(q3.y);

    float d = su.x * si.x + su.y * si.y + su.z * si.z + su.w * si.w;
    #pragma unroll
    for (int m = 1; m < 16; m <<= 1) d += __shfl_xor(d, m, 64);
    if (lane == 0) out[b] = d * inv2;
}

// ---------------- launch ----------------

extern "C" void kernel_launch(void* const* d_in, const int* in_sizes, int n_in,
                              void* d_out, int out_size, void* d_ws, size_t ws_size,
                              hipStream_t stream) {
    const float* user_emb = (const float*)d_in[0];
    const float* item_emb = (const float*)d_in[1];
    const float* edge_vals = (const float*)d_in[2];
    const int* edge_u = (const int*)d_in[3];
    const int* edge_i = (const int*)d_in[4];
    const int* users = (const int*)d_in[5];
    const int* items = (const int*)d_in[6];
    float* out = (float*)d_out;

    const int U = in_sizes[0] / D;
    const int I = in_sizes[1] / D;
    const int E = in_sizes[2];
    const int B = in_sizes[5];

    const int nb_i = (I + (1 << SH_I) - 1) >> SH_I;
    const int nb_u = (U + (1 << SH_U) - 1) >> SH_U;
    const int tiles = (E + TILE - 1) / TILE;
    // cap: mean real + worst-case pad (PAD-1 per block) + variance slack
    const int cap_i = ((E / nb_i + tiles * (PAD - 1) + 1024 + 63) / 64) * 64;
    const int cap_u = ((E / nb_u + tiles * (PAD - 1) + 1024 + 63) / 64) * 64;

    // carve workspace (256B aligned)
    char* p = (char*)d_ws;
    size_t off = 0;
    auto alloc = [&](size_t bytes) -> char* {
        char* r = p + off;
        off = (off + bytes + 255) & ~(size_t)255;
        return r;
    };
    u32* ub16  = (u32*)alloc((size_t)U * (D / 2) * 4);  // packed bf16, 128B rows
    u32* ib16  = (u32*)alloc((size_t)I * (D / 2) * 4);
    u32* eu1   = (u32*)alloc((size_t)U * (D / 2) * 4);  // dense layer-1/2 tables
    u32* eu2   = (u32*)alloc((size_t)U * (D / 2) * 4);
    u32* ei1   = (u32*)alloc((size_t)I * (D / 2) * 4);
    u32* ei2   = (u32*)alloc((size_t)I * (D / 2) * 4);
    u32* eu3s  = (u32*)alloc((size_t)B * (D / 2) * 4);  // sampled layer-3 (by slot)
    u32* ei3s  = (u32*)alloc((size_t)B * (D / 2) * 4);
    u32* csr_u = (u32*)alloc((size_t)(E + 16) * 4);
    u32* csr_i = (u32*)alloc((size_t)(E + 16) * 4);
    int* rowp_u = (int*)alloc((size_t)(U + 1) * 4);
    int* rowp_i = (int*)alloc((size_t)(I + 1) * 4);
    int* cur_i  = (int*)alloc((size_t)nb_i * 4);
    int* cur_u  = (int*)alloc((size_t)nb_u * 4);
    int* rc_i   = (int*)alloc((size_t)nb_i * 4);
    int* rc_u   = (int*)alloc((size_t)nb_u * 4);
    int* bb_i   = (int*)alloc((size_t)nb_i * 4);
    int* bb_u   = (int*)alloc((size_t)nb_u * 4);
    u64* stg_i  = (u64*)alloc((size_t)nb_i * cap_i * 8);
    u64* stg_u  = (u64*)alloc((size_t)nb_u * cap_u * 8);
    if (off > ws_size) return;    // workspace too small -> fail loudly

    // 0. convert original embeddings to packed bf16 gather tables
    cvt_bf16_kernel<<<1024, 256, 0, stream>>>((const float2*)user_emb, ub16, (long)U * (D / 2));
    cvt_bf16_kernel<<<1024, 256, 0, stream>>>((const float2*)item_emb, ib16, (long)I * (D / 2));

    // 1. CSR build (both directions)
    init_cursors_kernel<<<1, 512, 0, stream>>>(cur_i, rc_i, nb_i, cap_i,
                                               cur_u, rc_u, nb_u, cap_u);
    passA_kernel<<<tiles, 512, 0, stream>>>(edge_u, edge_i, edge_vals, E,
                                            cur_i, rc_i, cur_u, rc_u,
                                            stg_i, stg_u);
    bucket_scan_kernel<<<1, 512, 0, stream>>>(rc_i, nb_i, E, bb_i, rowp_i + I);
    bucket_scan_kernel<<<1, 512, 0, stream>>>(rc_u, nb_u, E, bb_u, rowp_u + U);
    passB_kernel<<<nb_i + nb_u, 1024, 0, stream>>>(nb_i, cap_i, I, nb_u, cap_u, U,
                                                   cur_i, cur_u, rc_i, rc_u,
                                                   bb_i, bb_u,
                                                   stg_i, stg_u, rowp_i, rowp_u,
                                                   csr_i, csr_u);

    // 2. propagation: layers 1-2 dense, layer 3 only for sampled rows
    int blk_i = (I + 3) / 4;
    int blk_u = (U + 3) / 4;
    int blk_s = (B + 3) / 4;
    spmm_kernel<0><<<blk_i, 256, 0, stream>>>(rowp_i, csr_i, ub16, ei1, nullptr, I);
    spmm_kernel<0><<<blk_u, 256, 0, stream>>>(rowp_u, csr_u, ib16, eu1, nullptr, U);
    spmm_kernel<0><<<blk_i, 256, 0, stream>>>(rowp_i, csr_i, eu1, ei2, nullptr, I);
    spmm_kernel<0><<<blk_u, 256, 0, stream>>>(rowp_u, csr_u, ei1, eu2, nullptr, U);
    spmm_kernel<1><<<blk_s, 256, 0, stream>>>(rowp_i, csr_i, eu2, ei3s, items, B);
    spmm_kernel<1><<<blk_s, 256, 0, stream>>>(rowp_u, csr_u, ei2, eu3s, users, B);

    // 3. final scores for sampled pairs: sum four layers, dot, scale by 1/16
    int blk_sc = (B * 16 + 255) / 256;
    score_kernel<<<blk_sc, 256, 0, stream>>>(user_emb, item_emb,
                                             eu1, eu2, eu3s, ei1, ei2, ei3s,
                                             users, items, out, B, 0.0625f);
}

// Round 16
// 300.527 us; speedup vs baseline: 1.6544x; 1.0355x over previous
//
#include <hip/hip_runtime.h>
#include <stdint.h>

#define D 64          // embedding dim
#define SH_I 8        // item rows per bucket = 256
#define SH_U 9        // user rows per bucket = 512
#define EPT 12        // edges per thread in passA
#define TILE 6144     // 512 threads * EPT
#define PAD 8         // staging segment alignment (records) = 64B sector
#define SRT_CAP 18944 // LDS sorted-CSR buffer (4B recs) = 74KB

typedef unsigned long long u64;
typedef unsigned int u32;

#define DUMMY64 0xFFFFFFFF00000000ull

// ---------------- bf16 helpers ----------------

__device__ __forceinline__ u32 bf16_rne(float f) {
    u32 x = __float_as_uint(f);
    return (x + 0x7fffu + ((x >> 16) & 1u)) >> 16;
}
__device__ __forceinline__ u32 pack2_bf16(float a, float b) {
    return bf16_rne(a) | (bf16_rne(b) << 16);
}
__device__ __forceinline__ float blo(u32 w) { return __uint_as_float(w << 16); }
__device__ __forceinline__ float bhi(u32 w) { return __uint_as_float(w & 0xffff0000u); }

// f32 pairs -> packed bf16 (u32 holds 2 elems), row-major 128B rows
__global__ __launch_bounds__(256)
void cvt_bf16_kernel(const float2* __restrict__ src, u32* __restrict__ dst, long n2) {
    long i = (long)blockIdx.x * blockDim.x + threadIdx.x;
    long stride = (long)gridDim.x * blockDim.x;
    for (; i < n2; i += stride) {
        float2 f = src[i];
        dst[i] = pack2_bf16(f.x, f.y);
    }
}

// ---------------- scan helpers ----------------

__device__ __forceinline__ int excl_scan_512t(int v, int* wsum) {
    int tid = threadIdx.x, lane = tid & 63, wid = tid >> 6;
    int x = v;
    #pragma unroll
    for (int d = 1; d < 64; d <<= 1) { int t = __shfl_up(x, d, 64); if (lane >= d) x += t; }
    if (lane == 63) wsum[wid] = x;
    __syncthreads();
    if (tid < 8) {
        int y = wsum[tid];
        #pragma unroll
        for (int d = 1; d < 8; d <<= 1) { int t = __shfl_up(y, d, 8); if (tid >= d) y += t; }
        wsum[tid] = y;
    }
    __syncthreads();
    return ((wid > 0) ? wsum[wid - 1] : 0) + x - v;
}

__device__ __forceinline__ int excl_scan_1024t(int v, int* wsum16) {
    int tid = threadIdx.x, lane = tid & 63, wid = tid >> 6;
    int x = v;
    #pragma unroll
    for (int d = 1; d < 64; d <<= 1) { int t = __shfl_up(x, d, 64); if (lane >= d) x += t; }
    if (lane == 63) wsum16[wid] = x;
    __syncthreads();
    if (tid < 16) {
        int y = wsum16[tid];
        #pragma unroll
        for (int d = 1; d < 16; d <<= 1) { int t = __shfl_up(y, d, 16); if (tid >= d) y += t; }
        wsum16[tid] = y;
    }
    __syncthreads();
    return ((wid > 0) ? wsum16[wid - 1] : 0) + x - v;
}

// ---------------- CSR build ----------------
// Edge record (4B): [val_bf16_sans_sign:15 | src:17]   (val > 0 always)
// Staging record (8B): [dst_in_bucket:32][rec:32]; dummy has dst = 0xFFFFFFFF

__global__ __launch_bounds__(512)
void init_cursors_kernel(int* cur_i, int* rc_i, int nb_i, int cap_i,
                         int* cur_u, int* rc_u, int nb_u, int cap_u) {
    int t = threadIdx.x;
    if (t < nb_i) { cur_i[t] = t * cap_i; rc_i[t] = 0; }
    if (t < nb_u) { cur_u[t] = t * cap_u; rc_u[t] = 0; }
}

// LDS-sorted binning: histogram -> LDS scan -> LDS scatter -> per-bucket
// burst copy to 64B-aligned global segments (full-sector writes, amp ~1).
// Burst copy: 4 buckets per wave x 16 lanes each.
__global__ __launch_bounds__(512)
void passA_kernel(const int* __restrict__ eu, const int* __restrict__ ei,
                  const float* __restrict__ ev, int E,
                  int* __restrict__ cur_i, int* __restrict__ rc_i,
                  int* __restrict__ cur_u, int* __restrict__ rc_u,
                  u64* __restrict__ stg_i, u64* __restrict__ stg_u) {
    __shared__ u64 stage[TILE];            // 48KB sorted staging
    __shared__ int cnt[256], loffs[256], gbase[256];
    __shared__ int wsum[8];
    int tid = threadIdx.x;
    long tile0 = (long)blockIdx.x * TILE;
    int uu[EPT], ii[EPT], lo[EPT];
    u32 vv[EPT];
    #pragma unroll
    for (int j = 0; j < EPT; ++j) {
        long e = tile0 + tid + j * 512;
        if (e < E) {
            uu[j] = eu[e]; ii[j] = ei[e];
            vv[j] = bf16_rne(ev[e]) & 0x7fffu;
        } else {
            uu[j] = -1;
        }
    }

    // ---------- direction: dst = item (bucket = ii>>SH_I, src = uu) ----------
    if (tid < 256) cnt[tid] = 0;
    __syncthreads();
    #pragma unroll
    for (int j = 0; j < EPT; ++j)
        if (uu[j] >= 0) lo[j] = atomicAdd(&cnt[ii[j] >> SH_I], 1);
    __syncthreads();
    {
        int c = (tid < 256) ? cnt[tid] : 0;
        int excl = excl_scan_512t(c, wsum);
        if (tid < 256) {
            loffs[tid] = excl;
            if (c) {
                int cp = (c + PAD - 1) & ~(PAD - 1);
                gbase[tid] = atomicAdd(&cur_i[tid], cp);
                atomicAdd(&rc_i[tid], c);
            }
        }
    }
    __syncthreads();
    #pragma unroll
    for (int j = 0; j < EPT; ++j) {
        if (uu[j] >= 0) {
            int b = ii[j] >> SH_I;
            u32 rec = (vv[j] << 17) | (u32)uu[j];
            stage[loffs[b] + lo[j]] =
                ((u64)(u32)(ii[j] & ((1 << SH_I) - 1)) << 32) | rec;
        }
    }
    __syncthreads();
    {
        int w = tid >> 6, lane = tid & 63;
        int sub = lane >> 4, l16 = lane & 15;
        for (int b = w * 4 + sub; b < 256; b += 32) {
            int c = cnt[b];
            if (!c) continue;
            int cp = (c + PAD - 1) & ~(PAD - 1);
            int lb = loffs[b];
            long gb = gbase[b];
            for (int r = l16; r < cp; r += 16)
                stg_i[gb + r] = (r < c) ? stage[lb + r] : DUMMY64;
        }
    }
    __syncthreads();

    // ---------- direction: dst = user (bucket = uu>>SH_U, src = ii) ----------
    if (tid < 256) cnt[tid] = 0;
    __syncthreads();
    #pragma unroll
    for (int j = 0; j < EPT; ++j)
        if (uu[j] >= 0) lo[j] = atomicAdd(&cnt[uu[j] >> SH_U], 1);
    __syncthreads();
    {
        int c = (tid < 256) ? cnt[tid] : 0;
        int excl = excl_scan_512t(c, wsum);
        if (tid < 256) {
            loffs[tid] = excl;
            if (c) {
                int cp = (c + PAD - 1) & ~(PAD - 1);
                gbase[tid] = atomicAdd(&cur_u[tid], cp);
                atomicAdd(&rc_u[tid], c);
            }
        }
    }
    __syncthreads();
    #pragma unroll
    for (int j = 0; j < EPT; ++j) {
        if (uu[j] >= 0) {
            int b = uu[j] >> SH_U;
            u32 rec = (vv[j] << 17) | (u32)ii[j];
            stage[loffs[b] + lo[j]] =
                ((u64)(u32)(uu[j] & ((1 << SH_U) - 1)) << 32) | rec;
        }
    }
    __syncthreads();
    {
        int w = tid >> 6, lane = tid & 63;
        int sub = lane >> 4, l16 = lane & 15;
        for (int b = w * 4 + sub; b < 256; b += 32) {
            int c = cnt[b];
            if (!c) continue;
            int cp = (c + PAD - 1) & ~(PAD - 1);
            int lb = loffs[b];
            long gb = gbase[b];
            for (int r = l16; r < cp; r += 16)
                stg_u[gb + r] = (r < c) ? stage[lb + r] : DUMMY64;
        }
    }
}

// both directions' bucket scans in one launch (saves serial launch latency)
__global__ __launch_bounds__(512)
void bucket_scan2_kernel(const int* __restrict__ rc_i, int nb_i,
                         int* __restrict__ bb_i, int* __restrict__ sent_i,
                         const int* __restrict__ rc_u, int nb_u,
                         int* __restrict__ bb_u, int* __restrict__ sent_u, int E) {
    __shared__ int wsum[8];
    int tid = threadIdx.x;
    int v = (tid < nb_i) ? rc_i[tid] : 0;
    int excl = excl_scan_512t(v, wsum);
    if (tid < nb_i) bb_i[tid] = excl;
    if (tid == 0) *sent_i = E;
    __syncthreads();
    v = (tid < nb_u) ? rc_u[tid] : 0;
    excl = excl_scan_512t(v, wsum);
    if (tid < nb_u) bb_u[tid] = excl;
    if (tid == 0) *sent_u = E;
}

// Per bucket: histogram -> scan -> rowptr; scatter records into LDS sorted by
// row; burst-copy the sorted run to CSR (coalesced, write amp ~1).
__global__ __launch_bounds__(1024)
void passB_kernel(int nb_i, int cap_i, int N_i,
                  int nb_u, int cap_u, int N_u,
                  const int* __restrict__ cur_i, const int* __restrict__ cur_u,
                  const int* __restrict__ rc_i, const int* __restrict__ rc_u,
                  const int* __restrict__ bb_i, const int* __restrict__ bb_u,
                  const u64* __restrict__ stg_i, const u64* __restrict__ stg_u,
                  int* __restrict__ rowp_i, int* __restrict__ rowp_u,
                  u32* __restrict__ csr_i, u32* __restrict__ csr_u) {
    __shared__ u32 srt[SRT_CAP];
    __shared__ int lcnt[512];
    __shared__ int wsum[16];
    int b = blockIdx.x;
    int dir_item = (b < nb_i);
    int bb = dir_item ? b : b - nb_i;
    int SH = dir_item ? SH_I : SH_U;
    int cap = dir_item ? cap_i : cap_u;
    int N = dir_item ? N_i : N_u;
    const u64* stg = dir_item ? stg_i : stg_u;
    int ebase = dir_item ? bb_i[bb] : bb_u[bb];
    int scount = (dir_item ? cur_i[bb] : cur_u[bb]) - bb * cap;   // incl. dummies
    int realcnt = dir_item ? rc_i[bb] : rc_u[bb];
    int* rowp = dir_item ? rowp_i : rowp_u;
    u32* csr = dir_item ? csr_i : csr_u;

    int rows0 = bb << SH;
    int nrows = min(1 << SH, N - rows0);
    int tid = threadIdx.x;
    const uint4* stg4 = (const uint4*)(stg + (size_t)bb * cap);
    int npair = scount >> 1;                 // scount is a multiple of PAD=8

    if (tid < 512) lcnt[tid] = 0;
    __syncthreads();
    for (int k = tid; k < npair; k += 1024) {
        uint4 w = stg4[k];
        if ((int)w.y >= 0) atomicAdd(&lcnt[(int)w.y], 1);
        if ((int)w.w >= 0) atomicAdd(&lcnt[(int)w.w], 1);
    }
    __syncthreads();
    int v = (tid < 512) ? lcnt[tid] : 0;
    int excl = excl_scan_1024t(v, wsum);
    if (tid < 512) lcnt[tid] = excl;         // becomes bucket-local running cursor
    if (tid < nrows) rowp[rows0 + tid] = ebase + excl;
    __syncthreads();
    // scatter into LDS sorted by row (guard vs statistically-impossible overflow)
    for (int k = tid; k < npair; k += 1024) {
        uint4 w = stg4[k];
        if ((int)w.y >= 0) {
            int p = atomicAdd(&lcnt[(int)w.y], 1);
            if (p < SRT_CAP) srt[p] = w.x;
        }
        if ((int)w.w >= 0) {
            int p = atomicAdd(&lcnt[(int)w.w], 1);
            if (p < SRT_CAP) srt[p] = w.z;
        }
    }
    __syncthreads();
    // coalesced burst copy to global CSR
    int n = min(realcnt, SRT_CAP);
    for (int k = tid; k < n; k += 1024)
        csr[ebase + k] = srt[k];
}

// ---------------- propagation ----------------

// Wave-per-row SpMM over packed-bf16 128B rows, uint4 gathers.
// lane = (g:3 | el:3): 8 edge-subgroups x unroll 2 = 16 edges in flight;
// el indexes the row's uint4 (8 bf16 = dims el*8..el*8+7).
// 4B records: src = rec & 0x1ffff, val_f32_bits = (rec & 0xfffe0000) >> 1.
// SAMPLED: row = idx[slot], output keyed by slot (for last layer).
template<int SAMPLED>
__global__ __launch_bounds__(256)
void spmm_kernel(const int* __restrict__ rowptr, const u32* __restrict__ csr,
                 const u32* __restrict__ src16, u32* __restrict__ dst16,
                 const int* __restrict__ idx, int nrows) {
    int slot = blockIdx.x * 4 + (threadIdx.x >> 6);
    if (slot >= nrows) return;
    int row = SAMPLED ? idx[slot] : slot;
    int lane = threadIdx.x & 63;
    int g = lane >> 3;
    int el = lane & 7;
    int beg = rowptr[row], end = rowptr[row + 1];
    const uint4* SB = (const uint4*)src16 + el;   // row stride = 8 uint4 (128B)
    float A0[8] = {0,0,0,0,0,0,0,0}, A1[8] = {0,0,0,0,0,0,0,0};
    for (int k = beg + g; k < end; k += 16) {
        u32 r0 = csr[k];
        u32 r1 = csr[k + 8];
        bool m1 = (k + 8) < end;
        int s0 = (int)(r0 & 0x1ffffu);
        int s1 = m1 ? (int)(r1 & 0x1ffffu) : 0;
        float v0 = __uint_as_float((r0 & 0xfffe0000u) >> 1);
        float v1 = m1 ? __uint_as_float((r1 & 0xfffe0000u) >> 1) : 0.f;
        uint4 w0 = SB[(size_t)s0 * 8];
        uint4 w1 = SB[(size_t)s1 * 8];
        A0[0] += v0 * blo(w0.x); A0[1] += v0 * bhi(w0.x);
        A0[2] += v0 * blo(w0.y); A0[3] += v0 * bhi(w0.y);
        A0[4] += v0 * blo(w0.z); A0[5] += v0 * bhi(w0.z);
        A0[6] += v0 * blo(w0.w); A0[7] += v0 * bhi(w0.w);
        A1[0] += v1 * blo(w1.x); A1[1] += v1 * bhi(w1.x);
        A1[2] += v1 * blo(w1.y); A1[3] += v1 * bhi(w1.y);
        A1[4] += v1 * blo(w1.z); A1[5] += v1 * bhi(w1.z);
        A1[6] += v1 * blo(w1.w); A1[7] += v1 * bhi(w1.w);
    }
    float a[8];
    #pragma unroll
    for (int j = 0; j < 8; ++j) a[j] = A0[j] + A1[j];
    #pragma unroll
    for (int m = 8; m < 64; m <<= 1) {
        #pragma unroll
        for (int j = 0; j < 8; ++j) a[j] += __shfl_xor(a[j], m, 64);
    }
    if (g == 0) {
        uint4 o;
        o.x = pack2_bf16(a[0], a[1]);
        o.y = pack2_bf16(a[2], a[3]);
        o.z = pack2_bf16(a[4], a[5]);
        o.w = pack2_bf16(a[6], a[7]);
        ((uint4*)dst16)[(size_t)slot * 8 + el] = o;
    }
}

// Final score: per sampled pair, sum orig f32 + e1,e2 (by id) + e3 (by slot),
// dot, scale. 16 lanes per pair.
__global__ __launch_bounds__(256)
void score_kernel(const float* __restrict__ user_emb, const float* __restrict__ item_emb,
                  const u32* __restrict__ eu1, const u32* __restrict__ eu2,
                  const u32* __restrict__ eu3s,
                  const u32* __restrict__ ei1, const u32* __restrict__ ei2,
                  const u32* __restrict__ ei3s,
                  const int* __restrict__ users, const int* __restrict__ items,
                  float* __restrict__ out, int B, float inv2) {
    int gid = blockIdx.x * blockDim.x + threadIdx.x;
    int b = gid >> 4;
    int lane = gid & 15;
    if (b >= B) return;
    int u = users[b], it = items[b];

    float4 su = ((const float4*)(user_emb + (size_t)u * D))[lane];
    uint2 p1 = ((const uint2*)eu1)[(size_t)u * 16 + lane];
    uint2 p2 = ((const uint2*)eu2)[(size_t)u * 16 + lane];
    uint2 p3 = ((const uint2*)eu3s)[(size_t)b * 16 + lane];
    su.x += blo(p1.x) + blo(p2.x) + blo(p3.x);
    su.y += bhi(p1.x) + bhi(p2.x) + bhi(p3.x);
    su.z += blo(p1.y) + blo(p2.y) + blo(p3.y);
    su.w += bhi(p1.y) + bhi(p2.y) + bhi(p3.y);

    float4 si = ((const float4*)(item_emb + (size_t)it * D))[lane];
    uint2 q1 = ((const uint2*)ei1)[(size_t)it * 16 + lane];
    uint2 q2 = ((const uint2*)ei2)[(size_t)it * 16 + lane];
    uint2 q3 = ((const uint2*)ei3s)[(size_t)b * 16 + lane];
    si.x += blo(q1.x) + blo(q2.x) + blo(q3.x);
    si.y += bhi(q1.x) + bhi(q2.x) + bhi(q3.x);
    si.z += blo(q1.y) + blo(q2.y) + blo(q3.y);
    si.w += bhi(q1.y) + bhi(q2.y) + bhi(q3.y);

    float d = su.x * si.x + su.y * si.y + su.z * si.z + su.w * si.w;
    #pragma unroll
    for (int m = 1; m < 16; m <<= 1) d += __shfl_xor(d, m, 64);
    if (lane == 0) out[b] = d * inv2;
}

// ---------------- launch ----------------

extern "C" void kernel_launch(void* const* d_in, const int* in_sizes, int n_in,
                              void* d_out, int out_size, void* d_ws, size_t ws_size,
                              hipStream_t stream) {
    const float* user_emb = (const float*)d_in[0];
    const float* item_emb = (const float*)d_in[1];
    const float* edge_vals = (const float*)d_in[2];
    const int* edge_u = (const int*)d_in[3];
    const int* edge_i = (const int*)d_in[4];
    const int* users = (const int*)d_in[5];
    const int* items = (const int*)d_in[6];
    float* out = (float*)d_out;

    const int U = in_sizes[0] / D;
    const int I = in_sizes[1] / D;
    const int E = in_sizes[2];
    const int B = in_sizes[5];

    const int nb_i = (I + (1 << SH_I) - 1) >> SH_I;
    const int nb_u = (U + (1 << SH_U) - 1) >> SH_U;
    const int tiles = (E + TILE - 1) / TILE;
    // cap: mean real + worst-case pad (PAD-1 per block) + variance slack
    const int cap_i = ((E / nb_i + tiles * (PAD - 1) + 1024 + 63) / 64) * 64;
    const int cap_u = ((E / nb_u + tiles * (PAD - 1) + 1024 + 63) / 64) * 64;

    // carve workspace (256B aligned)
    char* p = (char*)d_ws;
    size_t off = 0;
    auto alloc = [&](size_t bytes) -> char* {
        char* r = p + off;
        off = (off + bytes + 255) & ~(size_t)255;
        return r;
    };
    u32* ub16  = (u32*)alloc((size_t)U * (D / 2) * 4);  // packed bf16, 128B rows
    u32* ib16  = (u32*)alloc((size_t)I * (D / 2) * 4);
    u32* eu1   = (u32*)alloc((size_t)U * (D / 2) * 4);  // dense layer-1/2 tables
    u32* eu2   = (u32*)alloc((size_t)U * (D / 2) * 4);
    u32* ei1   = (u32*)alloc((size_t)I * (D / 2) * 4);
    u32* ei2   = (u32*)alloc((size_t)I * (D / 2) * 4);
    u32* eu3s  = (u32*)alloc((size_t)B * (D / 2) * 4);  // sampled layer-3 (by slot)
    u32* ei3s  = (u32*)alloc((size_t)B * (D / 2) * 4);
    u32* csr_u = (u32*)alloc((size_t)(E + 16) * 4);
    u32* csr_i = (u32*)alloc((size_t)(E + 16) * 4);
    int* rowp_u = (int*)alloc((size_t)(U + 1) * 4);
    int* rowp_i = (int*)alloc((size_t)(I + 1) * 4);
    int* cur_i  = (int*)alloc((size_t)nb_i * 4);
    int* cur_u  = (int*)alloc((size_t)nb_u * 4);
    int* rc_i   = (int*)alloc((size_t)nb_i * 4);
    int* rc_u   = (int*)alloc((size_t)nb_u * 4);
    int* bb_i   = (int*)alloc((size_t)nb_i * 4);
    int* bb_u   = (int*)alloc((size_t)nb_u * 4);
    u64* stg_i  = (u64*)alloc((size_t)nb_i * cap_i * 8);
    u64* stg_u  = (u64*)alloc((size_t)nb_u * cap_u * 8);
    if (off > ws_size) return;    // workspace too small -> fail loudly

    // 0. convert original embeddings to packed bf16 gather tables
    cvt_bf16_kernel<<<1024, 256, 0, stream>>>((const float2*)user_emb, ub16, (long)U * (D / 2));
    cvt_bf16_kernel<<<1024, 256, 0, stream>>>((const float2*)item_emb, ib16, (long)I * (D / 2));

    // 1. CSR build (both directions)
    init_cursors_kernel<<<1, 512, 0, stream>>>(cur_i, rc_i, nb_i, cap_i,
                                               cur_u, rc_u, nb_u, cap_u);
    passA_kernel<<<tiles, 512, 0, stream>>>(edge_u, edge_i, edge_vals, E,
                                            cur_i, rc_i, cur_u, rc_u,
                                            stg_i, stg_u);
    bucket_scan2_kernel<<<1, 512, 0, stream>>>(rc_i, nb_i, bb_i, rowp_i + I,
                                               rc_u, nb_u, bb_u, rowp_u + U, E);
    passB_kernel<<<nb_i + nb_u, 1024, 0, stream>>>(nb_i, cap_i, I, nb_u, cap_u, U,
                                                   cur_i, cur_u, rc_i, rc_u,
                                                   bb_i, bb_u,
                                                   stg_i, stg_u, rowp_i, rowp_u,
                                                   csr_i, csr_u);

    // 2. propagation: layers 1-2 dense, layer 3 only for sampled rows
    int blk_i = (I + 3) / 4;
    int blk_u = (U + 3) / 4;
    int blk_s = (B + 3) / 4;
    spmm_kernel<0><<<blk_i, 256, 0, stream>>>(rowp_i, csr_i, ub16, ei1, nullptr, I);
    spmm_kernel<0><<<blk_u, 256, 0, stream>>>(rowp_u, csr_u, ib16, eu1, nullptr, U);
    spmm_kernel<0><<<blk_i, 256, 0, stream>>>(rowp_i, csr_i, eu1, ei2, nullptr, I);
    spmm_kernel<0><<<blk_u, 256, 0, stream>>>(rowp_u, csr_u, ei1, eu2, nullptr, U);
    spmm_kernel<1><<<blk_s, 256, 0, stream>>>(rowp_i, csr_i, eu2, ei3s, items, B);
    spmm_kernel<1><<<blk_s, 256, 0, stream>>>(rowp_u, csr_u, ei2, eu3s, users, B);

    // 3. final scores for sampled pairs: sum four layers, dot, scale by 1/16
    int blk_sc = (B * 16 + 255) / 256;
    score_kernel<<<blk_sc, 256, 0, stream>>>(user_emb, item_emb,
                                             eu1, eu2, eu3s, ei1, ei2, ei3s,
                                             users, items, out, B, 0.0625f);
}